// Round 3
// baseline (55733.466 us; speedup 1.0000x reference)
//
#include <hip/hip_runtime.h>
#include <stdint.h>

// ---------------------------------------------------------------------------
// trajectory2seq_attn: GRU encoder (2 layers, S=512) + greedy attn decoder (T=64)
// Precision strategy: all GEMMs via fp16 hi/lo split (a = hi + 2^-11*lo),
// 3 MFMA products (hi*hi, hi*lo, lo*hi), fp32 accum -> ~numpy-fp32 accuracy
// (needed so the argmax feedback never flips vs the fp32 reference).
// Round 4: persistent encoder v2 — STATIC 56KB LDS (no dynamic-LDS launch
// risk), 512 blocks (2/CU, 8 waves/CU), 12 W-rows per block, load-based
// barrier polling (no RMW storm), bounded waits. Decoder unchanged.
// ---------------------------------------------------------------------------

#define BB 64
#define SS 512
#define TT 64
#define HH 1024
#define VV 1024
#define BH 65536   // B*H
#define SH 524288  // S*H
#define OFF_HID  4194304           // B*T*V
#define OFF_ATTN 4325376           // + L*B*H

typedef _Float16 half8  __attribute__((ext_vector_type(8)));
typedef float    floatx4 __attribute__((ext_vector_type(4)));

struct P {
  const float *x, *emb;
  const float *eWih0, *eWhh0, *ebih0, *ebhh0;
  const float *dWih0, *dWhh0, *dbih0, *dbhh0;
  const float *eWih1, *eWhh1, *ebih1, *ebhh1;
  const float *dWih1, *dWhh1, *dbih1, *dbhh1;
  const float *hqW, *hqb, *combW, *combb, *fcW, *fcb;
  uint32_t* enc_i;                 // [B][S][H] packed (hi | lo<<16)
  _Float16 *W0h,*W0l;              // enc l0 Whh grouped [256][12][1024]
  _Float16 *W1h,*W1l;              // enc l1 [Whh1|Wih1] grouped [256][12][2048]
  _Float16 *embh,*embl,*T0h,*T0l;  // T0 = emb @ dWih0^T + dbih0  [V][H] pairs
  _Float16 *wih0dh,*wih0dl,*wih1dh,*wih1dl,*whh0dh,*whh0dl,*whh1dh,*whh1dl;
  _Float16 *hqh,*hql,*combh,*combl,*fch,*fcl;
  _Float16 *h0h,*h0l,*h1h,*h1l;    // [2][B*H] parity-double-buffered enc states
  _Float16 *dh0h,*dh0l,*dh1h,*dh1l;// decoder states [B*H]
  _Float16 *cath,*catl;            // [B][2048] = [h1 | att] pairs
  _Float16 *ch,*cl;                // comb output pairs [B*H]
  float *u0,*u1,*w1x,*q;           // fp32 [B*H]
  float *attp_o;                   // [B][2][H]
  float *attp_ml;                  // [B][2][2]  (m,l per half)
  float *sc63;                     // [B][S] raw scores at t=63
  unsigned long long* amax;        // [B][128] argmax partials
  unsigned* bar;                   // persistent-kernel grid barrier counter
  float* dout;
};

struct GSet { const _Float16 *Wh, *Wl, *Ah, *Al; const float *bias; float *out; };

// ---------------- helpers ----------------
__device__ __forceinline__ void splitf(float x, _Float16& hi, _Float16& lo){
  _Float16 h = (_Float16)x; hi = h;
  lo = (_Float16)((x - (float)h) * 2048.0f);
}
__device__ __forceinline__ float reconf(_Float16 hi, _Float16 lo){
  return fmaf((float)lo, 1.0f/2048.0f, (float)hi);
}
__device__ __forceinline__ float recon_u32(uint32_t w){
  float hi = (float)__builtin_bit_cast(_Float16, (unsigned short)(w & 0xffffu));
  float lo = (float)__builtin_bit_cast(_Float16, (unsigned short)(w >> 16));
  return fmaf(lo, 1.0f/2048.0f, hi);
}
__device__ __forceinline__ uint32_t pack_pair(float x){
  _Float16 hi, lo; splitf(x, hi, lo);
  return (uint32_t)__builtin_bit_cast(unsigned short, hi)
       | ((uint32_t)__builtin_bit_cast(unsigned short, lo) << 16);
}
__device__ __forceinline__ unsigned ordf(float f){
  unsigned u = __float_as_uint(f);
  return (u & 0x80000000u) ? ~u : (u | 0x80000000u);
}

// device-scope grid barrier (monotonic counter, reset by k_zero each launch).
// Poll with agent-scope atomic LOADS (no RMW serialization); RMW probe every
// 64th poll as a staleness safety net. fail bit = 0x40000000: set on bounded
// timeout; all pollers bail => kernel terminates (wrong result, no hang).
__device__ __forceinline__ int gbar(unsigned* bar, unsigned target, int bound){
  __shared__ int oks;
  __syncthreads();
  if (threadIdx.x == 0){
    int ok = 1;
    __threadfence();                 // release: publish this block's writes
    __hip_atomic_fetch_add(bar, 1u, __ATOMIC_RELAXED, __HIP_MEMORY_SCOPE_AGENT);
    int it = 0;
    for (;;){
      unsigned v = ((it & 63) == 63)
        ? __hip_atomic_fetch_add(bar, 0u, __ATOMIC_RELAXED, __HIP_MEMORY_SCOPE_AGENT)
        : __hip_atomic_load(bar, __ATOMIC_RELAXED, __HIP_MEMORY_SCOPE_AGENT);
      if (v >= 0x40000000u){ ok = 0; break; }
      if (v >= target) break;
      ++it;
      if (bound && it > bound){
        __hip_atomic_fetch_add(bar, 0x40000000u, __ATOMIC_RELAXED, __HIP_MEMORY_SCOPE_AGENT);
        ok = 0; break;
      }
      __builtin_amdgcn_s_sleep(8);
    }
    __threadfence();                 // acquire: drop stale cached lines
    oks = ok;
  }
  __syncthreads();
  return oks;
}

// ---------------- split-precision GEMM core (decoder + t0) ----------------
// D[m,n] = sum_k A[m,k]*W[n,k],  m in 0..63 (4 waves x 16), n = block-local W row.
template<int NT, int KH, bool SPLIT>
__device__ __forceinline__ void gemm_core(
    const _Float16* __restrict__ Ah0, const _Float16* __restrict__ Al0,
    const _Float16* __restrict__ Ah1, const _Float16* __restrict__ Al1,
    int sA,
    const _Float16* __restrict__ Wh, const _Float16* __restrict__ Wl,
    int nrows, _Float16* ldsW, float* accOut)
{
  const int tid = threadIdx.x, lane = tid & 63, wave = tid >> 6;
  const int mA = (wave<<4) + (lane & 15);
  const int kb = ((lane>>4) << 3);
  const int wstride = KH << 10;
  floatx4 aH[NT], aM1[NT], aM2[NT];
  int ne[NT];
  const _Float16* bh_base[NT];
  const _Float16* bl_base[NT];
  #pragma unroll
  for (int nt=0; nt<NT; ++nt){
    int nn = (lane & 15) + (nt<<4);
    ne[nt] = nn < nrows ? nn : nrows - 1;   // clamp pad rows (outputs masked later)
    bh_base[nt] = ldsW + ne[nt]*1032 + kb;
    aH[nt]  = floatx4{0.f,0.f,0.f,0.f};
    aM1[nt] = floatx4{0.f,0.f,0.f,0.f};
    aM2[nt] = floatx4{0.f,0.f,0.f,0.f};
  }
  #pragma unroll
  for (int kh=0; kh<KH; ++kh){
    __syncthreads();
    const int iters = (nrows*128 + 255) >> 8;
    for (int it=0; it<iters; ++it){
      int idx = tid + (it<<8);
      int row = idx >> 7, col = (idx & 127) << 3;
      if (row < nrows)
        *(half8*)(ldsW + row*1032 + col) =
            *(const half8*)(Wh + row*wstride + (kh<<10) + col);
    }
    __syncthreads();
    const _Float16* ah_p = ((KH==2 && kh==1) ? Ah1 : Ah0) + mA*sA + kb;
    const _Float16* al_p = ((KH==2 && kh==1) ? Al1 : Al0) + mA*sA + kb;
    #pragma unroll
    for (int nt=0; nt<NT; ++nt) bl_base[nt] = Wl + ne[nt]*wstride + (kh<<10) + kb;
    #pragma unroll 4
    for (int ks=0; ks<32; ++ks){
      half8 ah = *(const half8*)(ah_p + (ks<<5));
      half8 al = *(const half8*)(al_p + (ks<<5));
      #pragma unroll
      for (int nt=0; nt<NT; ++nt){
        half8 bh = *(const half8*)(bh_base[nt] + (ks<<5));
        half8 bl = *(const half8*)(bl_base[nt] + (ks<<5));
        aH[nt]  = __builtin_amdgcn_mfma_f32_16x16x32_f16(ah, bh, aH[nt],  0,0,0);
        aM1[nt] = __builtin_amdgcn_mfma_f32_16x16x32_f16(ah, bl, aM1[nt], 0,0,0);
        aM2[nt] = __builtin_amdgcn_mfma_f32_16x16x32_f16(al, bh, aM2[nt], 0,0,0);
      }
    }
    if (SPLIT){
      #pragma unroll
      for (int nt=0; nt<NT; ++nt){
        #pragma unroll
        for (int r=0;r<4;++r)
          accOut[(kh*NT + nt)*4 + r] = aH[nt][r] + (aM1[nt][r] + aM2[nt][r]) * (1.f/2048.f);
        aH[nt]  = floatx4{0.f,0.f,0.f,0.f};
        aM1[nt] = floatx4{0.f,0.f,0.f,0.f};
        aM2[nt] = floatx4{0.f,0.f,0.f,0.f};
      }
    }
  }
  if (!SPLIT){
    #pragma unroll
    for (int nt=0; nt<NT; ++nt)
      #pragma unroll
      for (int r=0;r<4;++r)
        accOut[nt*4 + r] = aH[nt][r] + (aM1[nt][r] + aM2[nt][r]) * (1.f/2048.f);
  }
}

// ---------------- prologue kernels ----------------
__global__ __launch_bounds__(256) void k_split(const float* __restrict__ src,
                                               _Float16* dh, _Float16* dl, int n){
  for (int i = blockIdx.x*256 + threadIdx.x; i < n; i += gridDim.x*256){
    _Float16 hi,lo; splitf(src[i],hi,lo); dh[i]=hi; dl[i]=lo;
  }
}

// enc l0 Whh grouped: [blk 0..255][rr 0..11][k], gate g = rr>>2, within col c = rr&3
// grow = g*1024 + blk*4 + c
__global__ __launch_bounds__(256) void k_rw0(P p){
  const int n = 256*12*1024;
  for (int i = blockIdx.x*256 + threadIdx.x; i < n; i += gridDim.x*256){
    int k = i & 1023; int rest = i >> 10; int rr = rest % 12; int blk = rest / 12;
    int grow = (rr>>2)*1024 + (blk<<2) + (rr&3);
    _Float16 hi,lo; splitf(p.eWhh0[grow*1024 + k],hi,lo);
    p.W0h[i]=hi; p.W0l[i]=lo;
  }
}
// enc l1 [Whh1|Wih1] grouped: [blk 0..255][rr 0..11][k 0..2047]
__global__ __launch_bounds__(256) void k_rw1(P p){
  const int n = 256*12*2048;
  for (int i = blockIdx.x*256 + threadIdx.x; i < n; i += gridDim.x*256){
    int k = i & 2047; int rest = i >> 11; int rr = rest % 12; int blk = rest / 12;
    int grow = (rr>>2)*1024 + (blk<<2) + (rr&3);
    float v = (k < 1024) ? p.eWhh1[grow*1024 + k] : p.eWih1[grow*1024 + (k-1024)];
    _Float16 hi,lo; splitf(v,hi,lo);
    p.W1h[i]=hi; p.W1l[i]=lo;
  }
}
__global__ __launch_bounds__(256) void k_zero(P p){
  int i = blockIdx.x*256 + threadIdx.x;   // grid 256 -> 65536 threads
  p.h1h[i] = (_Float16)0.f; p.h1l[i] = (_Float16)0.f;         // h1 parity 0
  p.h0h[BH + i] = (_Float16)0.f; p.h0l[BH + i] = (_Float16)0.f; // h0 parity 1
  if (blockIdx.x == 0 && threadIdx.x == 0) *p.bar = 0u;       // reset grid barrier
}
// T0[v][j] = emb[v] . dWih0[j] + dbih0[j], stored as pairs
__global__ __launch_bounds__(256) void k_t0(P p){
  __shared__ _Float16 ldsW[16*1032];
  const int ns = blockIdx.x & 63, mc = blockIdx.x >> 6;
  float acc[4];
  gemm_core<1,1,false>(p.embh + mc*65536, p.embl + mc*65536, nullptr, nullptr, 1024,
                       p.wih0dh + ns*16*1024, p.wih0dl + ns*16*1024, 16, ldsW, acc);
  const int lane = threadIdx.x & 63, wave = threadIdx.x >> 6;
  const int n = lane & 15, col = (ns<<4) + n;
  const float bv = p.dbih0[col];
  #pragma unroll
  for (int r=0;r<4;++r){
    int v = mc*64 + (wave<<4) + ((lane>>4)<<2) + r;
    _Float16 hi,lo; splitf(acc[r] + bv, hi, lo);
    p.T0h[v*1024 + col] = hi; p.T0l[v*1024 + col] = lo;
  }
}

// ---------------- encoder: persistent kernel v2 (static 56KB LDS) ----------
// 512 blocks (2/CU, 8 waves/CU). blocks 0..255: layer0, 256..511: layer1
// (pipelined: l0 t=e, l1 t=e-1). Each block owns 4 output columns (12 grouped
// gate rows). Weights LDS-resident: l0 hi+lo, l1 hi (lo streamed from L2/LLC).
// One grid barrier per epoch; h parity-double-buffered so a single barrier
// (write cur || read prv) suffices. GRU "hold" kept in regs, re-rounded via
// splitf/reconf so arithmetic is bit-identical to the multi-launch path.
__global__ __launch_bounds__(256,2) void k_encp(P p){
  __shared__ _Float16 ldsW[24768];       // l0: hi[12][1032] + lo[12][1032]; l1: hi[12][2056]
  __shared__ float ldsG[2*12*68];
  __shared__ float ldsC[12*4];
  const int tid = threadIdx.x, lane = tid & 63, wave = tid >> 6;
  const bool is0 = blockIdx.x < 256;
  const int blk = is0 ? (int)blockIdx.x : (int)blockIdx.x - 256;
  const int j0 = blk << 2;

  // ---- one-time staging: weights + per-row constants ----
  if (is0){
    const _Float16* gh = p.W0h + blk*12*1024;
    const _Float16* gl = p.W0l + blk*12*1024;
    _Float16* Wl = ldsW + 12*1032;
    for (int it = tid; it < 12*128; it += 256){
      int row = it >> 7, col = (it & 127) << 3;
      *(half8*)(ldsW + row*1032 + col) = *(const half8*)(gh + row*1024 + col);
      *(half8*)(Wl   + row*1032 + col) = *(const half8*)(gl + row*1024 + col);
    }
  } else {
    const _Float16* gh = p.W1h + blk*12*2048;
    for (int it = tid; it < 12*256; it += 256){
      int row = it >> 8, col = (it & 255) << 3;
      *(half8*)(ldsW + row*2056 + col) = *(const half8*)(gh + row*2048 + col);
    }
  }
  if (tid < 12){
    int grow = (tid>>2)*1024 + j0 + (tid & 3);
    if (is0){
      ldsC[tid*4+0] = p.eWih0[grow*2+0];
      ldsC[tid*4+1] = p.eWih0[grow*2+1];
      ldsC[tid*4+2] = p.ebih0[grow];
      ldsC[tid*4+3] = p.ebhh0[grow];
    } else {
      ldsC[tid*4+0] = p.ebih1[grow];
      ldsC[tid*4+1] = p.ebhh1[grow];
    }
  }

  // co-residency probe: bounded first barrier (fail -> all blocks exit fast)
  if (!gbar(p.bar, 512u, 2000000)) return;

  const int mA = (wave<<4) + (lane & 15);
  const int kb = ((lane>>4) << 3);
  const int nn = lane & 15;
  const int ne = nn < 12 ? nn : 11;        // clamp pad rows (masked on store)
  const int b_ep = tid & 63, c_ep = tid >> 6;   // epilogue: 64 b x 4 c = 256 thr
  const int col_ep = j0 + c_ep;
  float hold = 0.f;                        // this thread's own h[b][col], rounded

  for (int e = 0; e <= 512; ++e){
    const int cur = e & 1, prv = cur ^ 1;
    if (is0){
      if (e < 512){
        floatx4 aH{0.f,0.f,0.f,0.f}, aM1{0.f,0.f,0.f,0.f}, aM2{0.f,0.f,0.f,0.f};
        const _Float16* ah_p = p.h0h + prv*BH + mA*1024 + kb;
        const _Float16* al_p = p.h0l + prv*BH + mA*1024 + kb;
        const _Float16* bh_p = ldsW + ne*1032 + kb;
        const _Float16* bl_p = ldsW + 12*1032 + ne*1032 + kb;
        #pragma unroll 4
        for (int ks=0; ks<32; ++ks){
          half8 ah = *(const half8*)(ah_p + (ks<<5));
          half8 al = *(const half8*)(al_p + (ks<<5));
          half8 bh = *(const half8*)(bh_p + (ks<<5));
          half8 bl = *(const half8*)(bl_p + (ks<<5));
          aH  = __builtin_amdgcn_mfma_f32_16x16x32_f16(ah, bh, aH,  0,0,0);
          aM1 = __builtin_amdgcn_mfma_f32_16x16x32_f16(ah, bl, aM1, 0,0,0);
          aM2 = __builtin_amdgcn_mfma_f32_16x16x32_f16(al, bh, aM2, 0,0,0);
        }
        if (nn < 12){
          #pragma unroll
          for (int r=0;r<4;++r)
            ldsG[nn*68 + (wave<<4)+((lane>>4)<<2)+r] =
                aH[r] + (aM1[r] + aM2[r]) * (1.f/2048.f);
        }
        __syncthreads();
        {
          const int b = b_ep, c = c_ep, col = col_ep;
          float hr = ldsG[c*68+b]     + ldsC[c*4+3];
          float hz = ldsG[(4+c)*68+b] + ldsC[(4+c)*4+3];
          float hn = ldsG[(8+c)*68+b] + ldsC[(8+c)*4+3];
          float x0 = p.x[b*1024 + e], x1 = p.x[b*1024 + 512 + e];
          float xr = fmaf(x0, ldsC[c*4+0],     fmaf(x1, ldsC[c*4+1],     ldsC[c*4+2]));
          float xz = fmaf(x0, ldsC[(4+c)*4+0], fmaf(x1, ldsC[(4+c)*4+1], ldsC[(4+c)*4+2]));
          float xn = fmaf(x0, ldsC[(8+c)*4+0], fmaf(x1, ldsC[(8+c)*4+1], ldsC[(8+c)*4+2]));
          float rg = 1.0f/(1.0f + expf(-(xr+hr)));
          float zg = 1.0f/(1.0f + expf(-(xz+hz)));
          float ng = tanhf(xn + rg*hn);
          float hnew = (1.0f - zg)*ng + zg*hold;
          _Float16 hi,lo; splitf(hnew,hi,lo);
          hold = reconf(hi,lo);            // match reload-rounded baseline exactly
          p.h0h[cur*BH + b*1024 + col] = hi;
          p.h0l[cur*BH + b*1024 + col] = lo;
        }
      }
    } else {
      if (e >= 1){
        #pragma unroll
        for (int kh=0; kh<2; ++kh){
          floatx4 aH{0.f,0.f,0.f,0.f}, aM1{0.f,0.f,0.f,0.f}, aM2{0.f,0.f,0.f,0.f};
          const _Float16* ah_p = (kh ? p.h0h : p.h1h) + prv*BH + mA*1024 + kb;
          const _Float16* al_p = (kh ? p.h0l : p.h1l) + prv*BH + mA*1024 + kb;
          const _Float16* bh_p = ldsW + ne*2056 + (kh<<10) + kb;
          const _Float16* bl_p = p.W1l + blk*12*2048 + ne*2048 + (kh<<10) + kb;
          #pragma unroll 4
          for (int ks=0; ks<32; ++ks){
            half8 ah = *(const half8*)(ah_p + (ks<<5));
            half8 al = *(const half8*)(al_p + (ks<<5));
            half8 bh = *(const half8*)(bh_p + (ks<<5));
            half8 bl = *(const half8*)(bl_p + (ks<<5));
            aH  = __builtin_amdgcn_mfma_f32_16x16x32_f16(ah, bh, aH,  0,0,0);
            aM1 = __builtin_amdgcn_mfma_f32_16x16x32_f16(ah, bl, aM1, 0,0,0);
            aM2 = __builtin_amdgcn_mfma_f32_16x16x32_f16(al, bh, aM2, 0,0,0);
          }
          if (nn < 12){
            #pragma unroll
            for (int r=0;r<4;++r)
              ldsG[(kh*12+nn)*68 + (wave<<4)+((lane>>4)<<2)+r] =
                  aH[r] + (aM1[r] + aM2[r]) * (1.f/2048.f);
          }
        }
        __syncthreads();
        {
          const int b = b_ep, c = c_ep, col = col_ep;
          const int t = e - 1;
          float hr = ldsG[c*68+b]        + ldsC[c*4+1];
          float hz = ldsG[(4+c)*68+b]    + ldsC[(4+c)*4+1];
          float hn = ldsG[(8+c)*68+b]    + ldsC[(8+c)*4+1];
          float xr = ldsG[(12+c)*68+b]   + ldsC[c*4+0];
          float xz = ldsG[(12+4+c)*68+b] + ldsC[(4+c)*4+0];
          float xn = ldsG[(12+8+c)*68+b] + ldsC[(8+c)*4+0];
          float rg = 1.0f/(1.0f + expf(-(xr+hr)));
          float zg = 1.0f/(1.0f + expf(-(xz+hz)));
          float ng = tanhf(xn + rg*hn);
          float hnew = (1.0f - zg)*ng + zg*hold;
          _Float16 hi,lo; splitf(hnew,hi,lo);
          hold = reconf(hi,lo);            // match reload-rounded baseline exactly
          p.h1h[cur*BH + b*1024 + col] = hi;
          p.h1l[cur*BH + b*1024 + col] = lo;
          p.enc_i[b*SH + t*1024 + col] = pack_pair(hnew);
        }
      }
    }
    // ldsG/ldsW hazards across epochs are covered by gbar's internal syncthreads
    if (!gbar(p.bar, (unsigned)(e+2)*512u, 100000)) return;
  }
}

// ---------------- encoder epoch (fallback path, multi-launch, v2 layout) ----
__global__ __launch_bounds__(256,2) void k_enc(P p, int e){
  __shared__ _Float16 ldsW[24768];
  __shared__ float ldsG[2*12*68];
  __shared__ float ldsC[12*4];
  const int tid = threadIdx.x, lane = tid & 63, wave = tid >> 6;
  const bool is0 = blockIdx.x < 256;
  if (is0 && e >= 512) return;
  if (!is0 && e < 1) return;
  const int blk = is0 ? (int)blockIdx.x : (int)blockIdx.x - 256;
  const int j0 = blk << 2;

  if (is0){
    const _Float16* gh = p.W0h + blk*12*1024;
    const _Float16* gl = p.W0l + blk*12*1024;
    _Float16* Wl = ldsW + 12*1032;
    for (int it = tid; it < 12*128; it += 256){
      int row = it >> 7, col = (it & 127) << 3;
      *(half8*)(ldsW + row*1032 + col) = *(const half8*)(gh + row*1024 + col);
      *(half8*)(Wl   + row*1032 + col) = *(const half8*)(gl + row*1024 + col);
    }
  } else {
    const _Float16* gh = p.W1h + blk*12*2048;
    for (int it = tid; it < 12*256; it += 256){
      int row = it >> 8, col = (it & 255) << 3;
      *(half8*)(ldsW + row*2056 + col) = *(const half8*)(gh + row*2048 + col);
    }
  }
  if (tid < 12){
    int grow = (tid>>2)*1024 + j0 + (tid & 3);
    if (is0){
      ldsC[tid*4+0] = p.eWih0[grow*2+0];
      ldsC[tid*4+1] = p.eWih0[grow*2+1];
      ldsC[tid*4+2] = p.ebih0[grow];
      ldsC[tid*4+3] = p.ebhh0[grow];
    } else {
      ldsC[tid*4+0] = p.ebih1[grow];
      ldsC[tid*4+1] = p.ebhh1[grow];
    }
  }
  __syncthreads();

  const int cur = e & 1, prv = cur ^ 1;
  const int mA = (wave<<4) + (lane & 15);
  const int kb = ((lane>>4) << 3);
  const int nn = lane & 15;
  const int ne = nn < 12 ? nn : 11;
  const int b_ep = tid & 63, c_ep = tid >> 6;
  const int col_ep = j0 + c_ep;

  if (is0){
    floatx4 aH{0.f,0.f,0.f,0.f}, aM1{0.f,0.f,0.f,0.f}, aM2{0.f,0.f,0.f,0.f};
    const _Float16* ah_p = p.h0h + prv*BH + mA*1024 + kb;
    const _Float16* al_p = p.h0l + prv*BH + mA*1024 + kb;
    const _Float16* bh_p = ldsW + ne*1032 + kb;
    const _Float16* bl_p = ldsW + 12*1032 + ne*1032 + kb;
    #pragma unroll 4
    for (int ks=0; ks<32; ++ks){
      half8 ah = *(const half8*)(ah_p + (ks<<5));
      half8 al = *(const half8*)(al_p + (ks<<5));
      half8 bh = *(const half8*)(bh_p + (ks<<5));
      half8 bl = *(const half8*)(bl_p + (ks<<5));
      aH  = __builtin_amdgcn_mfma_f32_16x16x32_f16(ah, bh, aH,  0,0,0);
      aM1 = __builtin_amdgcn_mfma_f32_16x16x32_f16(ah, bl, aM1, 0,0,0);
      aM2 = __builtin_amdgcn_mfma_f32_16x16x32_f16(al, bh, aM2, 0,0,0);
    }
    if (nn < 12){
      #pragma unroll
      for (int r=0;r<4;++r)
        ldsG[nn*68 + (wave<<4)+((lane>>4)<<2)+r] =
            aH[r] + (aM1[r] + aM2[r]) * (1.f/2048.f);
    }
    __syncthreads();
    {
      const int b = b_ep, c = c_ep, col = col_ep;
      float hr = ldsG[c*68+b]     + ldsC[c*4+3];
      float hz = ldsG[(4+c)*68+b] + ldsC[(4+c)*4+3];
      float hn = ldsG[(8+c)*68+b] + ldsC[(8+c)*4+3];
      float x0 = p.x[b*1024 + e], x1 = p.x[b*1024 + 512 + e];
      float xr = fmaf(x0, ldsC[c*4+0],     fmaf(x1, ldsC[c*4+1],     ldsC[c*4+2]));
      float xz = fmaf(x0, ldsC[(4+c)*4+0], fmaf(x1, ldsC[(4+c)*4+1], ldsC[(4+c)*4+2]));
      float xn = fmaf(x0, ldsC[(8+c)*4+0], fmaf(x1, ldsC[(8+c)*4+1], ldsC[(8+c)*4+2]));
      float rg = 1.0f/(1.0f + expf(-(xr+hr)));
      float zg = 1.0f/(1.0f + expf(-(xz+hz)));
      float ng = tanhf(xn + rg*hn);
      float hold = reconf(p.h0h[prv*BH + b*1024 + col], p.h0l[prv*BH + b*1024 + col]);
      float hnew = (1.0f - zg)*ng + zg*hold;
      _Float16 hi,lo; splitf(hnew,hi,lo);
      p.h0h[cur*BH + b*1024 + col] = hi;
      p.h0l[cur*BH + b*1024 + col] = lo;
    }
  } else {
    #pragma unroll
    for (int kh=0; kh<2; ++kh){
      floatx4 aH{0.f,0.f,0.f,0.f}, aM1{0.f,0.f,0.f,0.f}, aM2{0.f,0.f,0.f,0.f};
      const _Float16* ah_p = (kh ? p.h0h : p.h1h) + prv*BH + mA*1024 + kb;
      const _Float16* al_p = (kh ? p.h0l : p.h1l) + prv*BH + mA*1024 + kb;
      const _Float16* bh_p = ldsW + ne*2056 + (kh<<10) + kb;
      const _Float16* bl_p = p.W1l + blk*12*2048 + ne*2048 + (kh<<10) + kb;
      #pragma unroll 4
      for (int ks=0; ks<32; ++ks){
        half8 ah = *(const half8*)(ah_p + (ks<<5));
        half8 al = *(const half8*)(al_p + (ks<<5));
        half8 bh = *(const half8*)(bh_p + (ks<<5));
        half8 bl = *(const half8*)(bl_p + (ks<<5));
        aH  = __builtin_amdgcn_mfma_f32_16x16x32_f16(ah, bh, aH,  0,0,0);
        aM1 = __builtin_amdgcn_mfma_f32_16x16x32_f16(ah, bl, aM1, 0,0,0);
        aM2 = __builtin_amdgcn_mfma_f32_16x16x32_f16(al, bh, aM2, 0,0,0);
      }
      if (nn < 12){
        #pragma unroll
        for (int r=0;r<4;++r)
          ldsG[(kh*12+nn)*68 + (wave<<4)+((lane>>4)<<2)+r] =
              aH[r] + (aM1[r] + aM2[r]) * (1.f/2048.f);
      }
    }
    __syncthreads();
    {
      const int b = b_ep, c = c_ep, col = col_ep;
      const int t = e - 1;
      float hr = ldsG[c*68+b]        + ldsC[c*4+1];
      float hz = ldsG[(4+c)*68+b]    + ldsC[(4+c)*4+1];
      float hn = ldsG[(8+c)*68+b]    + ldsC[(8+c)*4+1];
      float xr = ldsG[(12+c)*68+b]   + ldsC[c*4+0];
      float xz = ldsG[(12+4+c)*68+b] + ldsC[(4+c)*4+0];
      float xn = ldsG[(12+8+c)*68+b] + ldsC[(8+c)*4+0];
      float rg = 1.0f/(1.0f + expf(-(xr+hr)));
      float zg = 1.0f/(1.0f + expf(-(xz+hz)));
      float ng = tanhf(xn + rg*hn);
      float hold = reconf(p.h1h[prv*BH + b*1024 + col], p.h1l[prv*BH + b*1024 + col]);
      float hnew = (1.0f - zg)*ng + zg*hold;
      _Float16 hi,lo; splitf(hnew,hi,lo);
      p.h1h[cur*BH + b*1024 + col] = hi;
      p.h1l[cur*BH + b*1024 + col] = lo;
      p.enc_i[b*SH + t*1024 + col] = pack_pair(hnew);
    }
  }
}

// ---------------- generic dual small GEMM (decoder) ----------------
__global__ __launch_bounds__(256) void k_dgemm2(GSet a, GSet b){
  const int tid = threadIdx.x, lane = tid & 63, wave = tid >> 6;
  const GSet g = blockIdx.x < 128 ? a : b;
  const int blk = blockIdx.x & 127;
  __shared__ _Float16 ldsW[8*1032];
  float acc[4];
  gemm_core<1,1,false>(g.Ah, g.Al, nullptr, nullptr, 1024,
                       g.Wh + blk*8*1024, g.Wl + blk*8*1024, 8, ldsW, acc);
  int n = lane & 15;
  if (n < 8){
    int col = (blk<<3) + n;
    float bv = g.bias[col];
    #pragma unroll
    for (int r=0;r<4;++r){
      int m = (wave<<4)+((lane>>4)<<2)+r;
      g.out[m*1024 + col] = acc[r] + bv;
    }
  }
}

// ---------------- decoder elementwise kernels ----------------
// K0: argmax-finalize(t-1) + h0 = tanh(T0[tok] + u0) -> dh0 pairs
__global__ __launch_bounds__(256) void k_dec0(P p, int t){
  const int tid = threadIdx.x, b = blockIdx.x;
  __shared__ unsigned long long red[256];
  unsigned long long v = 0;
  if (t > 0 && tid < 128) v = p.amax[b*128 + tid];
  red[tid] = v; __syncthreads();
  for (int off=128; off>=1; off>>=1){
    if (tid < off){ unsigned long long o = red[tid+off]; if (o > red[tid]) red[tid] = o; }
    __syncthreads();
  }
  const int tokb = (t > 0) ? (1023 - (int)(red[0] & 0xffffffffULL)) : 0;
  #pragma unroll
  for (int i=0;i<4;++i){
    int h = tid + (i<<8);
    float val = tanhf(reconf(p.T0h[tokb*1024+h], p.T0l[tokb*1024+h]) + p.u0[b*1024+h]);
    _Float16 hi,lo; splitf(val,hi,lo);
    p.dh0h[b*1024+h]=hi; p.dh0l[b*1024+h]=lo;
  }
}
// K2: h1 = tanh(w1x + u1) -> dh1 pairs + cat[:, :1024]
__global__ __launch_bounds__(256) void k_dec2(P p){
  const int tid = threadIdx.x, b = blockIdx.x;
  #pragma unroll
  for (int i=0;i<4;++i){
    int h = tid + (i<<8);
    float val = tanhf(p.w1x[b*1024+h] + p.u1[b*1024+h]);
    _Float16 hi,lo; splitf(val,hi,lo);
    p.dh1h[b*1024+h]=hi; p.dh1l[b*1024+h]=lo;
    p.cath[b*2048+h]=hi; p.catl[b*2048+h]=lo;
  }
}
// flash attention: block = (b, half of 256 s); fused score+softmax+value, online.
__global__ __launch_bounds__(256) void k_flash(P p, int t){
  const int tid = threadIdx.x, lane = tid & 63, wave = tid >> 6;
  const int b = blockIdx.x >> 1, half = blockIdx.x & 1;
  const int s0 = half << 8;
  const bool last = (t == 63);
  float qv[16];
  #pragma unroll
  for (int i=0;i<16;++i) qv[i] = p.q[b*1024 + (i<<6) + lane];
  float ov[16];
  #pragma unroll
  for (int i=0;i<16;++i) ov[i] = 0.f;
  float mrun = -3.0e38f, lrun = 0.f;
  for (int si=0; si<64; ++si){
    int s = s0 + (wave<<6) + si;
    const uint32_t* ep = p.enc_i + b*SH + s*1024 + lane;
    float ef[16]; float partial = 0.f;
    #pragma unroll
    for (int i=0;i<16;++i){
      ef[i] = recon_u32(ep[i<<6]);
      partial = fmaf(ef[i], qv[i], partial);
    }
    #pragma unroll
    for (int off=32; off; off>>=1) partial += __shfl_xor(partial, off, 64);
    if (last && lane == 0) p.sc63[b*512 + s] = partial;
    float mnew = fmaxf(mrun, partial);
    float fac = __expf(mrun - mnew);
    float w   = __expf(partial - mnew);
    lrun = fmaf(lrun, fac, w);
    #pragma unroll
    for (int i=0;i<16;++i) ov[i] = fmaf(ov[i], fac, w*ef[i]);
    mrun = mnew;
  }
  __shared__ float ldsO[4][1024];
  __shared__ float ldsM[4], ldsL2[4];
  #pragma unroll
  for (int i=0;i<16;++i) ldsO[wave][(i<<6)+lane] = ov[i];
  if (lane == 0){ ldsM[wave] = mrun; ldsL2[wave] = lrun; }
  __syncthreads();
  float M = fmaxf(fmaxf(ldsM[0],ldsM[1]), fmaxf(ldsM[2],ldsM[3]));
  float f0 = __expf(ldsM[0]-M), f1 = __expf(ldsM[1]-M),
        f2 = __expf(ldsM[2]-M), f3 = __expf(ldsM[3]-M);
  if (tid == 0){
    p.attp_ml[b*4 + half*2 + 0] = M;
    p.attp_ml[b*4 + half*2 + 1] = f0*ldsL2[0] + f1*ldsL2[1] + f2*ldsL2[2] + f3*ldsL2[3];
  }
  #pragma unroll
  for (int i=0;i<4;++i){
    int h = tid + (i<<8);
    p.attp_o[(b*2+half)*1024 + h] =
        f0*ldsO[0][h] + f1*ldsO[1][h] + f2*ldsO[2][h] + f3*ldsO[3][h];
  }
}
// K5: combine halves -> att pairs into cat[:,1024:]; at t=63 also write aw output
__global__ __launch_bounds__(256) void k_dec5(P p, int t){
  const int tid = threadIdx.x, b = blockIdx.x;
  float m0 = p.attp_ml[b*4+0], l0 = p.attp_ml[b*4+1];
  float m1 = p.attp_ml[b*4+2], l1 = p.attp_ml[b*4+3];
  float M = fmaxf(m0,m1);
  float f0 = expf(m0-M), f1 = expf(m1-M);
  float invL = 1.0f/(f0*l0 + f1*l1);
  #pragma unroll
  for (int i=0;i<4;++i){
    int h = tid + (i<<8);
    float o = (f0*p.attp_o[(b*2+0)*1024+h] + f1*p.attp_o[(b*2+1)*1024+h]) * invL;
    _Float16 hi,lo; splitf(o,hi,lo);
    p.cath[b*2048 + 1024 + h] = hi; p.catl[b*2048 + 1024 + h] = lo;
  }
  if (t == 63){
    #pragma unroll
    for (int i=0;i<2;++i){
      int s = tid + (i<<8);
      p.dout[OFF_ATTN + b*512 + s] = expf(p.sc63[b*512+s] - M) * invL;
    }
  }
}
// K6: c = comb_W . [h1|att] + comb_b  -> c pairs
__global__ __launch_bounds__(256) void k_comb(P p){
  const int tid = threadIdx.x, lane = tid & 63, wave = tid >> 6;
  const int blk = blockIdx.x;
  __shared__ _Float16 ldsW[8*1032];
  float acc[4];
  gemm_core<1,2,false>(p.cath, p.catl, p.cath + 1024, p.catl + 1024, 2048,
                       p.combh + blk*8*2048, p.combl + blk*8*2048, 8, ldsW, acc);
  int n = lane & 15;
  if (n < 8){
    int col = (blk<<3) + n;
    float bv = p.combb[col];
    #pragma unroll
    for (int r=0;r<4;++r){
      int m = (wave<<4)+((lane>>4)<<2)+r;
      _Float16 hi,lo; splitf(acc[r] + bv, hi, lo);
      p.ch[m*1024 + col] = hi; p.cl[m*1024 + col] = lo;
    }
  }
}
// K7: logits = fc . c + fc_b -> d_out[b][t][:] + per-block argmax partials
__global__ __launch_bounds__(256) void k_fc(P p, int t){
  const int tid = threadIdx.x, lane = tid & 63, wave = tid >> 6;
  const int blk = blockIdx.x;
  __shared__ _Float16 ldsW[8*1032];
  __shared__ float ldsL[8][68];
  float acc[4];
  gemm_core<1,1,false>(p.ch, p.cl, nullptr, nullptr, 1024,
                       p.fch + blk*8*1024, p.fcl + blk*8*1024, 8, ldsW, acc);
  int n = lane & 15;
  if (n < 8){
    int col = (blk<<3) + n;
    float bv = p.fcb[col];
    #pragma unroll
    for (int r=0;r<4;++r){
      int m = (wave<<4)+((lane>>4)<<2)+r;
      float val = acc[r] + bv;
      p.dout[m*65536 + t*1024 + col] = val;
      ldsL[n][m] = val;
    }
  }
  __syncthreads();
  if (tid < 64){
    int b = tid; float best = -3.0e38f; int bi = 0;
    #pragma unroll
    for (int jj=0; jj<8; ++jj){
      float v = ldsL[jj][b];
      if (v > best){ best = v; bi = jj; }
    }
    unsigned long long pk = ((unsigned long long)ordf(best) << 32)
                          | (unsigned)(1023 - ((blk<<3) + bi));
    p.amax[b*128 + blk] = pk;
  }
}
// final hidden output [2][B][H]
__global__ __launch_bounds__(256) void k_hidden(P p){
  int idx = blockIdx.x*256 + threadIdx.x;   // grid 512 -> 131072
  int i = idx & 65535;
  float v = (idx >> 16) ? reconf(p.dh1h[i], p.dh1l[i]) : reconf(p.dh0h[i], p.dh0l[i]);
  p.dout[OFF_HID + idx] = v;
}

// ---------------- host ----------------
extern "C" void kernel_launch(void* const* d_in, const int* in_sizes, int n_in,
                              void* d_out, int out_size, void* d_ws, size_t ws_size,
                              hipStream_t stream)
{
  (void)in_sizes; (void)n_in; (void)out_size;
  P p;
  p.x     = (const float*)d_in[0];  p.emb   = (const float*)d_in[1];
  p.eWih0 = (const float*)d_in[2];  p.eWhh0 = (const float*)d_in[3];
  p.ebih0 = (const float*)d_in[4];  p.ebhh0 = (const float*)d_in[5];
  p.dWih0 = (const float*)d_in[6];  p.dWhh0 = (const float*)d_in[7];
  p.dbih0 = (const float*)d_in[8];  p.dbhh0 = (const float*)d_in[9];
  p.eWih1 = (const float*)d_in[10]; p.eWhh1 = (const float*)d_in[11];
  p.ebih1 = (const float*)d_in[12]; p.ebhh1 = (const float*)d_in[13];
  p.dWih1 = (const float*)d_in[14]; p.dWhh1 = (const float*)d_in[15];
  p.dbih1 = (const float*)d_in[16]; p.dbhh1 = (const float*)d_in[17];
  p.hqW   = (const float*)d_in[18]; p.hqb   = (const float*)d_in[19];
  p.combW = (const float*)d_in[20]; p.combb = (const float*)d_in[21];
  p.fcW   = (const float*)d_in[22]; p.fcb   = (const float*)d_in[23];
  p.dout  = (float*)d_out;

  char* base = (char*)d_ws; size_t off = 0;
  auto alloc = [&](size_t bytes)->char*{
    char* r = base + off; off = (off + bytes + 255) & ~(size_t)255; return r;
  };
  p.enc_i = (uint32_t*)alloc(33554432ULL*4);
  p.W0h = (_Float16*)alloc(3145728ULL*2);  p.W0l = (_Float16*)alloc(3145728ULL*2);
  p.W1h = (_Float16*)alloc(6291456ULL*2);  p.W1l = (_Float16*)alloc(6291456ULL*2);
  p.embh = (_Float16*)alloc(1048576ULL*2); p.embl = (_Float16*)alloc(1048576ULL*2);
  p.T0h  = (_Float16*)alloc(1048576ULL*2); p.T0l  = (_Float16*)alloc(1048576ULL*2);
  p.wih0dh=(_Float16*)alloc(1048576ULL*2); p.wih0dl=(_Float16*)alloc(1048576ULL*2);
  p.wih1dh=(_Float16*)alloc(1048576ULL*2); p.wih1dl=(_Float16*)alloc(1048576ULL*2);
  p.whh0dh=(_Float16*)alloc(1048576ULL*2); p.whh0dl=(_Float16*)alloc(1048576ULL*2);
  p.whh1dh=(_Float16*)alloc(1048576ULL*2); p.whh1dl=(_Float16*)alloc(1048576ULL*2);
  p.hqh  = (_Float16*)alloc(1048576ULL*2); p.hql  = (_Float16*)alloc(1048576ULL*2);
  p.combh= (_Float16*)alloc(2097152ULL*2); p.combl= (_Float16*)alloc(2097152ULL*2);
  p.fch  = (_Float16*)alloc(1048576ULL*2); p.fcl  = (_Float16*)alloc(1048576ULL*2);
  p.h0h  = (_Float16*)alloc(131072ULL*2);  p.h0l  = (_Float16*)alloc(131072ULL*2);
  p.h1h  = (_Float16*)alloc(131072ULL*2);  p.h1l  = (_Float16*)alloc(131072ULL*2);
  p.dh0h = (_Float16*)alloc(65536ULL*2);   p.dh0l = (_Float16*)alloc(65536ULL*2);
  p.dh1h = (_Float16*)alloc(65536ULL*2);   p.dh1l = (_Float16*)alloc(65536ULL*2);
  p.cath = (_Float16*)alloc(131072ULL*2);  p.catl = (_Float16*)alloc(131072ULL*2);
  p.ch   = (_Float16*)alloc(65536ULL*2);   p.cl   = (_Float16*)alloc(65536ULL*2);
  p.u0   = (float*)alloc(65536ULL*4);      p.u1   = (float*)alloc(65536ULL*4);
  p.w1x  = (float*)alloc(65536ULL*4);      p.q    = (float*)alloc(65536ULL*4);
  p.attp_o  = (float*)alloc(131072ULL*4);
  p.attp_ml = (float*)alloc(256ULL*4);
  p.sc63    = (float*)alloc(32768ULL*4);
  p.amax    = (unsigned long long*)alloc(8192ULL*8);
  p.bar     = (unsigned*)alloc(256);
  if (off > ws_size) return;   // workspace too small -> bench will report absmax fail

  // ---- prologue: split / reorder weights, tables, init ----
  k_split<<<2048,256,0,stream>>>(p.emb,   p.embh,   p.embl,   1048576);
  k_split<<<2048,256,0,stream>>>(p.dWih0, p.wih0dh, p.wih0dl, 1048576);
  k_split<<<2048,256,0,stream>>>(p.dWih1, p.wih1dh, p.wih1dl, 1048576);
  k_split<<<2048,256,0,stream>>>(p.dWhh0, p.whh0dh, p.whh0dl, 1048576);
  k_split<<<2048,256,0,stream>>>(p.dWhh1, p.whh1dh, p.whh1dl, 1048576);
  k_split<<<2048,256,0,stream>>>(p.hqW,   p.hqh,    p.hql,    1048576);
  k_split<<<2048,256,0,stream>>>(p.combW, p.combh,  p.combl,  2097152);
  k_split<<<2048,256,0,stream>>>(p.fcW,   p.fch,    p.fcl,    1048576);
  k_rw0<<<4096,256,0,stream>>>(p);
  k_rw1<<<4096,256,0,stream>>>(p);
  k_zero<<<256,256,0,stream>>>(p);
  k_t0<<<1024,256,0,stream>>>(p);

  // ---- encoder: persistent kernel v2 (static LDS, plain capturable launch) ----
  (void)hipGetLastError();  // clear any stale error
  k_encp<<<512,256,0,stream>>>(p);
  if (hipGetLastError() != hipSuccess){
    // should never fire (static LDS, legal config) -> known-good path
    for (int e=0; e<=512; ++e) k_enc<<<512,256,0,stream>>>(p, e);
  }

  // ---- decoder prologue: u0 = Whh0.h0_enc + bhh0 ; u1 = Whh1.h1_enc + bhh1 ----
  {
    GSet a{p.whh0dh, p.whh0dl, p.h0h + BH, p.h0l + BH, p.dbhh0, p.u0};
    GSet b{p.whh1dh, p.whh1dl, p.h1h,      p.h1l,      p.dbhh1, p.u1};
    k_dgemm2<<<256,256,0,stream>>>(a, b);
  }
  GSet sK1a{p.wih1dh, p.wih1dl, p.dh0h, p.dh0l, p.dbih1, p.w1x};
  GSet sK1b{p.whh0dh, p.whh0dl, p.dh0h, p.dh0l, p.dbhh0, p.u0};
  GSet sK3a{p.hqh,    p.hql,    p.dh1h, p.dh1l, p.hqb,   p.q};
  GSet sK3b{p.whh1dh, p.whh1dl, p.dh1h, p.dh1l, p.dbhh1, p.u1};

  // ---- decoder steps ----
  for (int t=0; t<64; ++t){
    k_dec0<<<64,256,0,stream>>>(p, t);          // argmax(t-1) + h0
    k_dgemm2<<<256,256,0,stream>>>(sK1a, sK1b); // w1x + u0(next)
    k_dec2<<<64,256,0,stream>>>(p);             // h1
    k_dgemm2<<<256,256,0,stream>>>(sK3a, sK3b); // q + u1(next)
    k_flash<<<128,256,0,stream>>>(p, t);        // fused attention
    k_dec5<<<64,256,0,stream>>>(p, t);          // att combine (+aw @ t=63)
    k_comb<<<128,256,0,stream>>>(p);            // comb projection
    k_fc<<<128,256,0,stream>>>(p, t);           // logits + argmax partials
  }
  k_hidden<<<512,256,0,stream>>>(p);
}

// Round 4
// 28653.769 us; speedup vs baseline: 1.9451x; 1.9451x over previous
//
#include <hip/hip_runtime.h>
#include <stdint.h>

// ---------------------------------------------------------------------------
// trajectory2seq_attn: GRU encoder (2 layers, S=512) + greedy attn decoder (T=64)
// Precision strategy: all GEMMs via fp16 hi/lo split (a = hi + 2^-11*lo),
// 3 MFMA products (hi*hi, hi*lo, lo*hi), fp32 accum -> ~numpy-fp32 accuracy
// (needed so the argmax feedback never flips vs the fp32 reference).
// Round 5: back to the PROVEN multi-launch encoder (stream order = barrier),
// but at 2 blocks/CU (512 blocks x 12 W-rows, ~56KB LDS, 8 waves/CU) for 2x
// latency hiding on the lo-plane/A streams. Persistent/grid-barrier path
// abandoned (3 rounds of evidence: slower than kernel boundaries).
// Decoder unchanged from the 30.3ms baseline.
// ---------------------------------------------------------------------------

#define BB 64
#define SS 512
#define TT 64
#define HH 1024
#define VV 1024
#define BH 65536   // B*H
#define SH 524288  // S*H
#define OFF_HID  4194304           // B*T*V
#define OFF_ATTN 4325376           // + L*B*H

typedef _Float16 half8  __attribute__((ext_vector_type(8)));
typedef float    floatx4 __attribute__((ext_vector_type(4)));

struct P {
  const float *x, *emb;
  const float *eWih0, *eWhh0, *ebih0, *ebhh0;
  const float *dWih0, *dWhh0, *dbih0, *dbhh0;
  const float *eWih1, *eWhh1, *ebih1, *ebhh1;
  const float *dWih1, *dWhh1, *dbih1, *dbhh1;
  const float *hqW, *hqb, *combW, *combb, *fcW, *fcb;
  uint32_t* enc_i;                 // [B][S][H] packed (hi | lo<<16)
  _Float16 *W0h,*W0l;              // enc l0 Whh grouped [256][12][1024]
  _Float16 *W1h,*W1l;              // enc l1 [Whh1|Wih1] grouped [256][12][2048]
  _Float16 *embh,*embl,*T0h,*T0l;  // T0 = emb @ dWih0^T + dbih0  [V][H] pairs
  _Float16 *wih0dh,*wih0dl,*wih1dh,*wih1dl,*whh0dh,*whh0dl,*whh1dh,*whh1dl;
  _Float16 *hqh,*hql,*combh,*combl,*fch,*fcl;
  _Float16 *h0h,*h0l,*h1h,*h1l;    // [2][B*H] parity-double-buffered enc states
  _Float16 *dh0h,*dh0l,*dh1h,*dh1l;// decoder states [B*H]
  _Float16 *cath,*catl;            // [B][2048] = [h1 | att] pairs
  _Float16 *ch,*cl;                // comb output pairs [B*H]
  float *u0,*u1,*w1x,*q;           // fp32 [B*H]
  float *attp_o;                   // [B][2][H]
  float *attp_ml;                  // [B][2][2]  (m,l per half)
  float *sc63;                     // [B][S] raw scores at t=63
  unsigned long long* amax;        // [B][128] argmax partials
  float* dout;
};

struct GSet { const _Float16 *Wh, *Wl, *Ah, *Al; const float *bias; float *out; };

// ---------------- helpers ----------------
__device__ __forceinline__ void splitf(float x, _Float16& hi, _Float16& lo){
  _Float16 h = (_Float16)x; hi = h;
  lo = (_Float16)((x - (float)h) * 2048.0f);
}
__device__ __forceinline__ float reconf(_Float16 hi, _Float16 lo){
  return fmaf((float)lo, 1.0f/2048.0f, (float)hi);
}
__device__ __forceinline__ float recon_u32(uint32_t w){
  float hi = (float)__builtin_bit_cast(_Float16, (unsigned short)(w & 0xffffu));
  float lo = (float)__builtin_bit_cast(_Float16, (unsigned short)(w >> 16));
  return fmaf(lo, 1.0f/2048.0f, hi);
}
__device__ __forceinline__ uint32_t pack_pair(float x){
  _Float16 hi, lo; splitf(x, hi, lo);
  return (uint32_t)__builtin_bit_cast(unsigned short, hi)
       | ((uint32_t)__builtin_bit_cast(unsigned short, lo) << 16);
}
__device__ __forceinline__ unsigned ordf(float f){
  unsigned u = __float_as_uint(f);
  return (u & 0x80000000u) ? ~u : (u | 0x80000000u);
}

// ---------------- split-precision GEMM core (decoder + t0) ----------------
// D[m,n] = sum_k A[m,k]*W[n,k],  m in 0..63 (4 waves x 16), n = block-local W row.
// A: per-k-half f16 plane pairs, row stride sA. W: grouped rows, stride KH*1024,
// hi plane staged through LDS per k-half, lo plane streamed from global.
template<int NT, int KH, bool SPLIT>
__device__ __forceinline__ void gemm_core(
    const _Float16* __restrict__ Ah0, const _Float16* __restrict__ Al0,
    const _Float16* __restrict__ Ah1, const _Float16* __restrict__ Al1,
    int sA,
    const _Float16* __restrict__ Wh, const _Float16* __restrict__ Wl,
    int nrows, _Float16* ldsW, float* accOut)
{
  const int tid = threadIdx.x, lane = tid & 63, wave = tid >> 6;
  const int mA = (wave<<4) + (lane & 15);
  const int kb = ((lane>>4) << 3);
  const int wstride = KH << 10;
  floatx4 aH[NT], aM1[NT], aM2[NT];
  int ne[NT];
  const _Float16* bh_base[NT];
  const _Float16* bl_base[NT];
  #pragma unroll
  for (int nt=0; nt<NT; ++nt){
    int nn = (lane & 15) + (nt<<4);
    ne[nt] = nn < nrows ? nn : nrows - 1;   // clamp pad rows (outputs masked later)
    bh_base[nt] = ldsW + ne[nt]*1032 + kb;
    aH[nt]  = floatx4{0.f,0.f,0.f,0.f};
    aM1[nt] = floatx4{0.f,0.f,0.f,0.f};
    aM2[nt] = floatx4{0.f,0.f,0.f,0.f};
  }
  #pragma unroll
  for (int kh=0; kh<KH; ++kh){
    __syncthreads();
    const int iters = (nrows*128 + 255) >> 8;
    for (int it=0; it<iters; ++it){
      int idx = tid + (it<<8);
      int row = idx >> 7, col = (idx & 127) << 3;
      if (row < nrows)
        *(half8*)(ldsW + row*1032 + col) =
            *(const half8*)(Wh + row*wstride + (kh<<10) + col);
    }
    __syncthreads();
    const _Float16* ah_p = ((KH==2 && kh==1) ? Ah1 : Ah0) + mA*sA + kb;
    const _Float16* al_p = ((KH==2 && kh==1) ? Al1 : Al0) + mA*sA + kb;
    #pragma unroll
    for (int nt=0; nt<NT; ++nt) bl_base[nt] = Wl + ne[nt]*wstride + (kh<<10) + kb;
    #pragma unroll 4
    for (int ks=0; ks<32; ++ks){
      half8 ah = *(const half8*)(ah_p + (ks<<5));
      half8 al = *(const half8*)(al_p + (ks<<5));
      #pragma unroll
      for (int nt=0; nt<NT; ++nt){
        half8 bh = *(const half8*)(bh_base[nt] + (ks<<5));
        half8 bl = *(const half8*)(bl_base[nt] + (ks<<5));
        aH[nt]  = __builtin_amdgcn_mfma_f32_16x16x32_f16(ah, bh, aH[nt],  0,0,0);
        aM1[nt] = __builtin_amdgcn_mfma_f32_16x16x32_f16(ah, bl, aM1[nt], 0,0,0);
        aM2[nt] = __builtin_amdgcn_mfma_f32_16x16x32_f16(al, bh, aM2[nt], 0,0,0);
      }
    }
    if (SPLIT){
      #pragma unroll
      for (int nt=0; nt<NT; ++nt){
        #pragma unroll
        for (int r=0;r<4;++r)
          accOut[(kh*NT + nt)*4 + r] = aH[nt][r] + (aM1[nt][r] + aM2[nt][r]) * (1.f/2048.f);
        aH[nt]  = floatx4{0.f,0.f,0.f,0.f};
        aM1[nt] = floatx4{0.f,0.f,0.f,0.f};
        aM2[nt] = floatx4{0.f,0.f,0.f,0.f};
      }
    }
  }
  if (!SPLIT){
    #pragma unroll
    for (int nt=0; nt<NT; ++nt)
      #pragma unroll
      for (int r=0;r<4;++r)
        accOut[nt*4 + r] = aH[nt][r] + (aM1[nt][r] + aM2[nt][r]) * (1.f/2048.f);
  }
}

// ---------------- prologue kernels ----------------
__global__ __launch_bounds__(256) void k_split(const float* __restrict__ src,
                                               _Float16* dh, _Float16* dl, int n){
  for (int i = blockIdx.x*256 + threadIdx.x; i < n; i += gridDim.x*256){
    _Float16 hi,lo; splitf(src[i],hi,lo); dh[i]=hi; dl[i]=lo;
  }
}

// enc l0 Whh grouped: [blk 0..255][rr 0..11][k], gate g = rr>>2, col c = rr&3
// grow = g*1024 + blk*4 + c
__global__ __launch_bounds__(256) void k_rw0(P p){
  const int n = 256*12*1024;
  for (int i = blockIdx.x*256 + threadIdx.x; i < n; i += gridDim.x*256){
    int k = i & 1023; int rest = i >> 10; int rr = rest % 12; int blk = rest / 12;
    int grow = (rr>>2)*1024 + (blk<<2) + (rr&3);
    _Float16 hi,lo; splitf(p.eWhh0[grow*1024 + k],hi,lo);
    p.W0h[i]=hi; p.W0l[i]=lo;
  }
}
// enc l1 [Whh1|Wih1] grouped: [blk 0..255][rr 0..11][k 0..2047]
__global__ __launch_bounds__(256) void k_rw1(P p){
  const int n = 256*12*2048;
  for (int i = blockIdx.x*256 + threadIdx.x; i < n; i += gridDim.x*256){
    int k = i & 2047; int rest = i >> 11; int rr = rest % 12; int blk = rest / 12;
    int grow = (rr>>2)*1024 + (blk<<2) + (rr&3);
    float v = (k < 1024) ? p.eWhh1[grow*1024 + k] : p.eWih1[grow*1024 + (k-1024)];
    _Float16 hi,lo; splitf(v,hi,lo);
    p.W1h[i]=hi; p.W1l[i]=lo;
  }
}
__global__ __launch_bounds__(256) void k_zero(P p){
  int i = blockIdx.x*256 + threadIdx.x;   // grid 256 -> 65536 threads
  p.h1h[i] = (_Float16)0.f; p.h1l[i] = (_Float16)0.f;         // h1 parity 0
  p.h0h[BH + i] = (_Float16)0.f; p.h0l[BH + i] = (_Float16)0.f; // h0 parity 1
}
// T0[v][j] = emb[v] . dWih0[j] + dbih0[j], stored as pairs
__global__ __launch_bounds__(256) void k_t0(P p){
  __shared__ _Float16 ldsW[16*1032];
  const int ns = blockIdx.x & 63, mc = blockIdx.x >> 6;
  float acc[4];
  gemm_core<1,1,false>(p.embh + mc*65536, p.embl + mc*65536, nullptr, nullptr, 1024,
                       p.wih0dh + ns*16*1024, p.wih0dl + ns*16*1024, 16, ldsW, acc);
  const int lane = threadIdx.x & 63, wave = threadIdx.x >> 6;
  const int n = lane & 15, col = (ns<<4) + n;
  const float bv = p.dbih0[col];
  #pragma unroll
  for (int r=0;r<4;++r){
    int v = mc*64 + (wave<<4) + ((lane>>4)<<2) + r;
    _Float16 hi,lo; splitf(acc[r] + bv, hi, lo);
    p.T0h[v*1024 + col] = hi; p.T0l[v*1024 + col] = lo;
  }
}

// ---------------- encoder epoch (multi-launch, 2 blocks/CU) ----------------
// 512 blocks: 0..255 layer0 (t=e), 256..511 layer1 (t=e-1, pipelined).
// Each block owns 4 output columns (12 grouped gate rows). ~56KB LDS ->
// 2 blocks/CU, 8 waves/CU (double the latency hiding of the 24-row layout).
// l0: W hi+lo LDS-resident per launch; l1: hi LDS, lo streamed from L2.
// Stream order between launches is the recurrence barrier (proven path).
__global__ __launch_bounds__(256,2) void k_enc(P p, int e){
  __shared__ _Float16 ldsW[24768];       // l0: hi[12][1032]+lo[12][1032]; l1: hi[12][2056]
  __shared__ float ldsG[2*12*68];
  __shared__ float ldsC[12*4];
  const int tid = threadIdx.x, lane = tid & 63, wave = tid >> 6;
  const bool is0 = blockIdx.x < 256;
  if (is0 && e >= 512) return;
  if (!is0 && e < 1) return;
  const int blk = is0 ? (int)blockIdx.x : (int)blockIdx.x - 256;
  const int j0 = blk << 2;

  if (is0){
    const _Float16* gh = p.W0h + blk*12*1024;
    const _Float16* gl = p.W0l + blk*12*1024;
    _Float16* Wl = ldsW + 12*1032;
    for (int it = tid; it < 12*128; it += 256){
      int row = it >> 7, col = (it & 127) << 3;
      *(half8*)(ldsW + row*1032 + col) = *(const half8*)(gh + row*1024 + col);
      *(half8*)(Wl   + row*1032 + col) = *(const half8*)(gl + row*1024 + col);
    }
  } else {
    const _Float16* gh = p.W1h + blk*12*2048;
    for (int it = tid; it < 12*256; it += 256){
      int row = it >> 8, col = (it & 255) << 3;
      *(half8*)(ldsW + row*2056 + col) = *(const half8*)(gh + row*2048 + col);
    }
  }
  if (tid < 12){
    int grow = (tid>>2)*1024 + j0 + (tid & 3);
    if (is0){
      ldsC[tid*4+0] = p.eWih0[grow*2+0];
      ldsC[tid*4+1] = p.eWih0[grow*2+1];
      ldsC[tid*4+2] = p.ebih0[grow];
      ldsC[tid*4+3] = p.ebhh0[grow];
    } else {
      ldsC[tid*4+0] = p.ebih1[grow];
      ldsC[tid*4+1] = p.ebhh1[grow];
    }
  }
  __syncthreads();

  const int cur = e & 1, prv = cur ^ 1;
  const int mA = (wave<<4) + (lane & 15);
  const int kb = ((lane>>4) << 3);
  const int nn = lane & 15;
  const int ne = nn < 12 ? nn : 11;        // clamp pad rows (masked on store)
  const int b_ep = tid & 63, c_ep = tid >> 6;   // epilogue: 64 b x 4 c = 256 thr
  const int col_ep = j0 + c_ep;

  if (is0){
    floatx4 aH{0.f,0.f,0.f,0.f}, aM1{0.f,0.f,0.f,0.f}, aM2{0.f,0.f,0.f,0.f};
    const _Float16* ah_p = p.h0h + prv*BH + mA*1024 + kb;
    const _Float16* al_p = p.h0l + prv*BH + mA*1024 + kb;
    const _Float16* bh_p = ldsW + ne*1032 + kb;
    const _Float16* bl_p = ldsW + 12*1032 + ne*1032 + kb;
    #pragma unroll 4
    for (int ks=0; ks<32; ++ks){
      half8 ah = *(const half8*)(ah_p + (ks<<5));
      half8 al = *(const half8*)(al_p + (ks<<5));
      half8 bh = *(const half8*)(bh_p + (ks<<5));
      half8 bl = *(const half8*)(bl_p + (ks<<5));
      aH  = __builtin_amdgcn_mfma_f32_16x16x32_f16(ah, bh, aH,  0,0,0);
      aM1 = __builtin_amdgcn_mfma_f32_16x16x32_f16(ah, bl, aM1, 0,0,0);
      aM2 = __builtin_amdgcn_mfma_f32_16x16x32_f16(al, bh, aM2, 0,0,0);
    }
    if (nn < 12){
      #pragma unroll
      for (int r=0;r<4;++r)
        ldsG[nn*68 + (wave<<4)+((lane>>4)<<2)+r] =
            aH[r] + (aM1[r] + aM2[r]) * (1.f/2048.f);
    }
    __syncthreads();
    {
      const int b = b_ep, c = c_ep, col = col_ep;
      float hr = ldsG[c*68+b]     + ldsC[c*4+3];
      float hz = ldsG[(4+c)*68+b] + ldsC[(4+c)*4+3];
      float hn = ldsG[(8+c)*68+b] + ldsC[(8+c)*4+3];
      float x0 = p.x[b*1024 + e], x1 = p.x[b*1024 + 512 + e];
      float xr = fmaf(x0, ldsC[c*4+0],     fmaf(x1, ldsC[c*4+1],     ldsC[c*4+2]));
      float xz = fmaf(x0, ldsC[(4+c)*4+0], fmaf(x1, ldsC[(4+c)*4+1], ldsC[(4+c)*4+2]));
      float xn = fmaf(x0, ldsC[(8+c)*4+0], fmaf(x1, ldsC[(8+c)*4+1], ldsC[(8+c)*4+2]));
      float rg = 1.0f/(1.0f + expf(-(xr+hr)));
      float zg = 1.0f/(1.0f + expf(-(xz+hz)));
      float ng = tanhf(xn + rg*hn);
      float hold = reconf(p.h0h[prv*BH + b*1024 + col], p.h0l[prv*BH + b*1024 + col]);
      float hnew = (1.0f - zg)*ng + zg*hold;
      _Float16 hi,lo; splitf(hnew,hi,lo);
      p.h0h[cur*BH + b*1024 + col] = hi;
      p.h0l[cur*BH + b*1024 + col] = lo;
    }
  } else {
    #pragma unroll
    for (int kh=0; kh<2; ++kh){
      floatx4 aH{0.f,0.f,0.f,0.f}, aM1{0.f,0.f,0.f,0.f}, aM2{0.f,0.f,0.f,0.f};
      const _Float16* ah_p = (kh ? p.h0h : p.h1h) + prv*BH + mA*1024 + kb;
      const _Float16* al_p = (kh ? p.h0l : p.h1l) + prv*BH + mA*1024 + kb;
      const _Float16* bh_p = ldsW + ne*2056 + (kh<<10) + kb;
      const _Float16* bl_p = p.W1l + blk*12*2048 + ne*2048 + (kh<<10) + kb;
      #pragma unroll 4
      for (int ks=0; ks<32; ++ks){
        half8 ah = *(const half8*)(ah_p + (ks<<5));
        half8 al = *(const half8*)(al_p + (ks<<5));
        half8 bh = *(const half8*)(bh_p + (ks<<5));
        half8 bl = *(const half8*)(bl_p + (ks<<5));
        aH  = __builtin_amdgcn_mfma_f32_16x16x32_f16(ah, bh, aH,  0,0,0);
        aM1 = __builtin_amdgcn_mfma_f32_16x16x32_f16(ah, bl, aM1, 0,0,0);
        aM2 = __builtin_amdgcn_mfma_f32_16x16x32_f16(al, bh, aM2, 0,0,0);
      }
      if (nn < 12){
        #pragma unroll
        for (int r=0;r<4;++r)
          ldsG[(kh*12+nn)*68 + (wave<<4)+((lane>>4)<<2)+r] =
              aH[r] + (aM1[r] + aM2[r]) * (1.f/2048.f);
      }
    }
    __syncthreads();
    {
      const int b = b_ep, c = c_ep, col = col_ep;
      const int t = e - 1;
      float hr = ldsG[c*68+b]        + ldsC[c*4+1];
      float hz = ldsG[(4+c)*68+b]    + ldsC[(4+c)*4+1];
      float hn = ldsG[(8+c)*68+b]    + ldsC[(8+c)*4+1];
      float xr = ldsG[(12+c)*68+b]   + ldsC[c*4+0];
      float xz = ldsG[(12+4+c)*68+b] + ldsC[(4+c)*4+0];
      float xn = ldsG[(12+8+c)*68+b] + ldsC[(8+c)*4+0];
      float rg = 1.0f/(1.0f + expf(-(xr+hr)));
      float zg = 1.0f/(1.0f + expf(-(xz+hz)));
      float ng = tanhf(xn + rg*hn);
      float hold = reconf(p.h1h[prv*BH + b*1024 + col], p.h1l[prv*BH + b*1024 + col]);
      float hnew = (1.0f - zg)*ng + zg*hold;
      _Float16 hi,lo; splitf(hnew,hi,lo);
      p.h1h[cur*BH + b*1024 + col] = hi;
      p.h1l[cur*BH + b*1024 + col] = lo;
      p.enc_i[b*SH + t*1024 + col] = pack_pair(hnew);
    }
  }
}

// ---------------- generic dual small GEMM (decoder) ----------------
__global__ __launch_bounds__(256) void k_dgemm2(GSet a, GSet b){
  const int tid = threadIdx.x, lane = tid & 63, wave = tid >> 6;
  const GSet g = blockIdx.x < 128 ? a : b;
  const int blk = blockIdx.x & 127;
  __shared__ _Float16 ldsW[8*1032];
  float acc[4];
  gemm_core<1,1,false>(g.Ah, g.Al, nullptr, nullptr, 1024,
                       g.Wh + blk*8*1024, g.Wl + blk*8*1024, 8, ldsW, acc);
  int n = lane & 15;
  if (n < 8){
    int col = (blk<<3) + n;
    float bv = g.bias[col];
    #pragma unroll
    for (int r=0;r<4;++r){
      int m = (wave<<4)+((lane>>4)<<2)+r;
      g.out[m*1024 + col] = acc[r] + bv;
    }
  }
}

// ---------------- decoder elementwise kernels ----------------
// K0: argmax-finalize(t-1) + h0 = tanh(T0[tok] + u0) -> dh0 pairs
__global__ __launch_bounds__(256) void k_dec0(P p, int t){
  const int tid = threadIdx.x, b = blockIdx.x;
  __shared__ unsigned long long red[256];
  unsigned long long v = 0;
  if (t > 0 && tid < 128) v = p.amax[b*128 + tid];
  red[tid] = v; __syncthreads();
  for (int off=128; off>=1; off>>=1){
    if (tid < off){ unsigned long long o = red[tid+off]; if (o > red[tid]) red[tid] = o; }
    __syncthreads();
  }
  const int tokb = (t > 0) ? (1023 - (int)(red[0] & 0xffffffffULL)) : 0;
  #pragma unroll
  for (int i=0;i<4;++i){
    int h = tid + (i<<8);
    float val = tanhf(reconf(p.T0h[tokb*1024+h], p.T0l[tokb*1024+h]) + p.u0[b*1024+h]);
    _Float16 hi,lo; splitf(val,hi,lo);
    p.dh0h[b*1024+h]=hi; p.dh0l[b*1024+h]=lo;
  }
}
// K2: h1 = tanh(w1x + u1) -> dh1 pairs + cat[:, :1024]
__global__ __launch_bounds__(256) void k_dec2(P p){
  const int tid = threadIdx.x, b = blockIdx.x;
  #pragma unroll
  for (int i=0;i<4;++i){
    int h = tid + (i<<8);
    float val = tanhf(p.w1x[b*1024+h] + p.u1[b*1024+h]);
    _Float16 hi,lo; splitf(val,hi,lo);
    p.dh1h[b*1024+h]=hi; p.dh1l[b*1024+h]=lo;
    p.cath[b*2048+h]=hi; p.catl[b*2048+h]=lo;
  }
}
// flash attention: block = (b, half of 256 s); fused score+softmax+value, online.
__global__ __launch_bounds__(256) void k_flash(P p, int t){
  const int tid = threadIdx.x, lane = tid & 63, wave = tid >> 6;
  const int b = blockIdx.x >> 1, half = blockIdx.x & 1;
  const int s0 = half << 8;
  const bool last = (t == 63);
  float qv[16];
  #pragma unroll
  for (int i=0;i<16;++i) qv[i] = p.q[b*1024 + (i<<6) + lane];
  float ov[16];
  #pragma unroll
  for (int i=0;i<16;++i) ov[i] = 0.f;
  float mrun = -3.0e38f, lrun = 0.f;
  for (int si=0; si<64; ++si){
    int s = s0 + (wave<<6) + si;
    const uint32_t* ep = p.enc_i + b*SH + s*1024 + lane;
    float ef[16]; float partial = 0.f;
    #pragma unroll
    for (int i=0;i<16;++i){
      ef[i] = recon_u32(ep[i<<6]);
      partial = fmaf(ef[i], qv[i], partial);
    }
    #pragma unroll
    for (int off=32; off; off>>=1) partial += __shfl_xor(partial, off, 64);
    if (last && lane == 0) p.sc63[b*512 + s] = partial;
    float mnew = fmaxf(mrun, partial);
    float fac = __expf(mrun - mnew);
    float w   = __expf(partial - mnew);
    lrun = fmaf(lrun, fac, w);
    #pragma unroll
    for (int i=0;i<16;++i) ov[i] = fmaf(ov[i], fac, w*ef[i]);
    mrun = mnew;
  }
  __shared__ float ldsO[4][1024];
  __shared__ float ldsM[4], ldsL2[4];
  #pragma unroll
  for (int i=0;i<16;++i) ldsO[wave][(i<<6)+lane] = ov[i];
  if (lane == 0){ ldsM[wave] = mrun; ldsL2[wave] = lrun; }
  __syncthreads();
  float M = fmaxf(fmaxf(ldsM[0],ldsM[1]), fmaxf(ldsM[2],ldsM[3]));
  float f0 = __expf(ldsM[0]-M), f1 = __expf(ldsM[1]-M),
        f2 = __expf(ldsM[2]-M), f3 = __expf(ldsM[3]-M);
  if (tid == 0){
    p.attp_ml[b*4 + half*2 + 0] = M;
    p.attp_ml[b*4 + half*2 + 1] = f0*ldsL2[0] + f1*ldsL2[1] + f2*ldsL2[2] + f3*ldsL2[3];
  }
  #pragma unroll
  for (int i=0;i<4;++i){
    int h = tid + (i<<8);
    p.attp_o[(b*2+half)*1024 + h] =
        f0*ldsO[0][h] + f1*ldsO[1][h] + f2*ldsO[2][h] + f3*ldsO[3][h];
  }
}
// K5: combine halves -> att pairs into cat[:,1024:]; at t=63 also write aw output
__global__ __launch_bounds__(256) void k_dec5(P p, int t){
  const int tid = threadIdx.x, b = blockIdx.x;
  float m0 = p.attp_ml[b*4+0], l0 = p.attp_ml[b*4+1];
  float m1 = p.attp_ml[b*4+2], l1 = p.attp_ml[b*4+3];
  float M = fmaxf(m0,m1);
  float f0 = expf(m0-M), f1 = expf(m1-M);
  float invL = 1.0f/(f0*l0 + f1*l1);
  #pragma unroll
  for (int i=0;i<4;++i){
    int h = tid + (i<<8);
    float o = (f0*p.attp_o[(b*2+0)*1024+h] + f1*p.attp_o[(b*2+1)*1024+h]) * invL;
    _Float16 hi,lo; splitf(o,hi,lo);
    p.cath[b*2048 + 1024 + h] = hi; p.catl[b*2048 + 1024 + h] = lo;
  }
  if (t == 63){
    #pragma unroll
    for (int i=0;i<2;++i){
      int s = tid + (i<<8);
      p.dout[OFF_ATTN + b*512 + s] = expf(p.sc63[b*512+s] - M) * invL;
    }
  }
}
// K6: c = comb_W . [h1|att] + comb_b  -> c pairs
__global__ __launch_bounds__(256) void k_comb(P p){
  const int tid = threadIdx.x, lane = tid & 63, wave = tid >> 6;
  const int blk = blockIdx.x;
  __shared__ _Float16 ldsW[8*1032];
  float acc[4];
  gemm_core<1,2,false>(p.cath, p.catl, p.cath + 1024, p.catl + 1024, 2048,
                       p.combh + blk*8*2048, p.combl + blk*8*2048, 8, ldsW, acc);
  int n = lane & 15;
  if (n < 8){
    int col = (blk<<3) + n;
    float bv = p.combb[col];
    #pragma unroll
    for (int r=0;r<4;++r){
      int m = (wave<<4)+((lane>>4)<<2)+r;
      _Float16 hi,lo; splitf(acc[r] + bv, hi, lo);
      p.ch[m*1024 + col] = hi; p.cl[m*1024 + col] = lo;
    }
  }
}
// K7: logits = fc . c + fc_b -> d_out[b][t][:] + per-block argmax partials
__global__ __launch_bounds__(256) void k_fc(P p, int t){
  const int tid = threadIdx.x, lane = tid & 63, wave = tid >> 6;
  const int blk = blockIdx.x;
  __shared__ _Float16 ldsW[8*1032];
  __shared__ float ldsL[8][68];
  float acc[4];
  gemm_core<1,1,false>(p.ch, p.cl, nullptr, nullptr, 1024,
                       p.fch + blk*8*1024, p.fcl + blk*8*1024, 8, ldsW, acc);
  int n = lane & 15;
  if (n < 8){
    int col = (blk<<3) + n;
    float bv = p.fcb[col];
    #pragma unroll
    for (int r=0;r<4;++r){
      int m = (wave<<4)+((lane>>4)<<2)+r;
      float val = acc[r] + bv;
      p.dout[m*65536 + t*1024 + col] = val;
      ldsL[n][m] = val;
    }
  }
  __syncthreads();
  if (tid < 64){
    int b = tid; float best = -3.0e38f; int bi = 0;
    #pragma unroll
    for (int jj=0; jj<8; ++jj){
      float v = ldsL[jj][b];
      if (v > best){ best = v; bi = jj; }
    }
    unsigned long long pk = ((unsigned long long)ordf(best) << 32)
                          | (unsigned)(1023 - ((blk<<3) + bi));
    p.amax[b*128 + blk] = pk;
  }
}
// final hidden output [2][B][H]
__global__ __launch_bounds__(256) void k_hidden(P p){
  int idx = blockIdx.x*256 + threadIdx.x;   // grid 512 -> 131072
  int i = idx & 65535;
  float v = (idx >> 16) ? reconf(p.dh1h[i], p.dh1l[i]) : reconf(p.dh0h[i], p.dh0l[i]);
  p.dout[OFF_HID + idx] = v;
}

// ---------------- host ----------------
extern "C" void kernel_launch(void* const* d_in, const int* in_sizes, int n_in,
                              void* d_out, int out_size, void* d_ws, size_t ws_size,
                              hipStream_t stream)
{
  (void)in_sizes; (void)n_in; (void)out_size;
  P p;
  p.x     = (const float*)d_in[0];  p.emb   = (const float*)d_in[1];
  p.eWih0 = (const float*)d_in[2];  p.eWhh0 = (const float*)d_in[3];
  p.ebih0 = (const float*)d_in[4];  p.ebhh0 = (const float*)d_in[5];
  p.dWih0 = (const float*)d_in[6];  p.dWhh0 = (const float*)d_in[7];
  p.dbih0 = (const float*)d_in[8];  p.dbhh0 = (const float*)d_in[9];
  p.eWih1 = (const float*)d_in[10]; p.eWhh1 = (const float*)d_in[11];
  p.ebih1 = (const float*)d_in[12]; p.ebhh1 = (const float*)d_in[13];
  p.dWih1 = (const float*)d_in[14]; p.dWhh1 = (const float*)d_in[15];
  p.dbih1 = (const float*)d_in[16]; p.dbhh1 = (const float*)d_in[17];
  p.hqW   = (const float*)d_in[18]; p.hqb   = (const float*)d_in[19];
  p.combW = (const float*)d_in[20]; p.combb = (const float*)d_in[21];
  p.fcW   = (const float*)d_in[22]; p.fcb   = (const float*)d_in[23];
  p.dout  = (float*)d_out;

  char* base = (char*)d_ws; size_t off = 0;
  auto alloc = [&](size_t bytes)->char*{
    char* r = base + off; off = (off + bytes + 255) & ~(size_t)255; return r;
  };
  p.enc_i = (uint32_t*)alloc(33554432ULL*4);
  p.W0h = (_Float16*)alloc(3145728ULL*2);  p.W0l = (_Float16*)alloc(3145728ULL*2);
  p.W1h = (_Float16*)alloc(6291456ULL*2);  p.W1l = (_Float16*)alloc(6291456ULL*2);
  p.embh = (_Float16*)alloc(1048576ULL*2); p.embl = (_Float16*)alloc(1048576ULL*2);
  p.T0h  = (_Float16*)alloc(1048576ULL*2); p.T0l  = (_Float16*)alloc(1048576ULL*2);
  p.wih0dh=(_Float16*)alloc(1048576ULL*2); p.wih0dl=(_Float16*)alloc(1048576ULL*2);
  p.wih1dh=(_Float16*)alloc(1048576ULL*2); p.wih1dl=(_Float16*)alloc(1048576ULL*2);
  p.whh0dh=(_Float16*)alloc(1048576ULL*2); p.whh0dl=(_Float16*)alloc(1048576ULL*2);
  p.whh1dh=(_Float16*)alloc(1048576ULL*2); p.whh1dl=(_Float16*)alloc(1048576ULL*2);
  p.hqh  = (_Float16*)alloc(1048576ULL*2); p.hql  = (_Float16*)alloc(1048576ULL*2);
  p.combh= (_Float16*)alloc(2097152ULL*2); p.combl= (_Float16*)alloc(2097152ULL*2);
  p.fch  = (_Float16*)alloc(1048576ULL*2); p.fcl  = (_Float16*)alloc(1048576ULL*2);
  p.h0h  = (_Float16*)alloc(131072ULL*2);  p.h0l  = (_Float16*)alloc(131072ULL*2);
  p.h1h  = (_Float16*)alloc(131072ULL*2);  p.h1l  = (_Float16*)alloc(131072ULL*2);
  p.dh0h = (_Float16*)alloc(65536ULL*2);   p.dh0l = (_Float16*)alloc(65536ULL*2);
  p.dh1h = (_Float16*)alloc(65536ULL*2);   p.dh1l = (_Float16*)alloc(65536ULL*2);
  p.cath = (_Float16*)alloc(131072ULL*2);  p.catl = (_Float16*)alloc(131072ULL*2);
  p.ch   = (_Float16*)alloc(65536ULL*2);   p.cl   = (_Float16*)alloc(65536ULL*2);
  p.u0   = (float*)alloc(65536ULL*4);      p.u1   = (float*)alloc(65536ULL*4);
  p.w1x  = (float*)alloc(65536ULL*4);      p.q    = (float*)alloc(65536ULL*4);
  p.attp_o  = (float*)alloc(131072ULL*4);
  p.attp_ml = (float*)alloc(256ULL*4);
  p.sc63    = (float*)alloc(32768ULL*4);
  p.amax    = (unsigned long long*)alloc(8192ULL*8);
  if (off > ws_size) return;   // workspace too small -> bench will report absmax fail

  // ---- prologue: split / reorder weights, tables, init ----
  k_split<<<2048,256,0,stream>>>(p.emb,   p.embh,   p.embl,   1048576);
  k_split<<<2048,256,0,stream>>>(p.dWih0, p.wih0dh, p.wih0dl, 1048576);
  k_split<<<2048,256,0,stream>>>(p.dWih1, p.wih1dh, p.wih1dl, 1048576);
  k_split<<<2048,256,0,stream>>>(p.dWhh0, p.whh0dh, p.whh0dl, 1048576);
  k_split<<<2048,256,0,stream>>>(p.dWhh1, p.whh1dh, p.whh1dl, 1048576);
  k_split<<<2048,256,0,stream>>>(p.hqW,   p.hqh,    p.hql,    1048576);
  k_split<<<2048,256,0,stream>>>(p.combW, p.combh,  p.combl,  2097152);
  k_split<<<2048,256,0,stream>>>(p.fcW,   p.fch,    p.fcl,    1048576);
  k_rw0<<<4096,256,0,stream>>>(p);
  k_rw1<<<4096,256,0,stream>>>(p);
  k_zero<<<256,256,0,stream>>>(p);
  k_t0<<<1024,256,0,stream>>>(p);

  // ---- encoder: 513 pipelined epochs, 512 blocks (2/CU) each ----
  for (int e=0; e<=512; ++e) k_enc<<<512,256,0,stream>>>(p, e);

  // ---- decoder prologue: u0 = Whh0.h0_enc + bhh0 ; u1 = Whh1.h1_enc + bhh1 ----
  {
    GSet a{p.whh0dh, p.whh0dl, p.h0h + BH, p.h0l + BH, p.dbhh0, p.u0};
    GSet b{p.whh1dh, p.whh1dl, p.h1h,      p.h1l,      p.dbhh1, p.u1};
    k_dgemm2<<<256,256,0,stream>>>(a, b);
  }
  GSet sK1a{p.wih1dh, p.wih1dl, p.dh0h, p.dh0l, p.dbih1, p.w1x};
  GSet sK1b{p.whh0dh, p.whh0dl, p.dh0h, p.dh0l, p.dbhh0, p.u0};
  GSet sK3a{p.hqh,    p.hql,    p.dh1h, p.dh1l, p.hqb,   p.q};
  GSet sK3b{p.whh1dh, p.whh1dl, p.dh1h, p.dh1l, p.dbhh1, p.u1};

  // ---- decoder steps ----
  for (int t=0; t<64; ++t){
    k_dec0<<<64,256,0,stream>>>(p, t);          // argmax(t-1) + h0
    k_dgemm2<<<256,256,0,stream>>>(sK1a, sK1b); // w1x + u0(next)
    k_dec2<<<64,256,0,stream>>>(p);             // h1
    k_dgemm2<<<256,256,0,stream>>>(sK3a, sK3b); // q + u1(next)
    k_flash<<<128,256,0,stream>>>(p, t);        // fused attention
    k_dec5<<<64,256,0,stream>>>(p, t);          // att combine (+aw @ t=63)
    k_comb<<<128,256,0,stream>>>(p);            // comb projection
    k_fc<<<128,256,0,stream>>>(p, t);           // logits + argmax partials
  }
  k_hidden<<<512,256,0,stream>>>(p);
}